// Round 9
// baseline (53.716 us; speedup 1.0000x reference)
//
#include <hip/hip_runtime.h>

// PointPillarsScatter, round 9 (= round 7 with compile fix): inverse-map
// gather with
//  - nontemporal (streaming) stores via clang ext_vector float4 (v4f)
//  - readfirstlane'd uniform geometry -> scalar/32-bit address arithmetic
//  - wave-uniform skip of vf loads for all-empty quad groups
// Structure: memset idxmap(-1) -> build_idx -> gather (write-once, coalesced).

typedef float v4f __attribute__((ext_vector_type(4)));

__global__ void pps_build_idx(const int* __restrict__ coords,
                              const int* __restrict__ nz_p,
                              const int* __restrict__ ny_p,
                              const int* __restrict__ nx_p,
                              int* __restrict__ idxmap, int n_points) {
    int n = blockIdx.x * blockDim.x + threadIdx.x;
    if (n >= n_points) return;
    int nz = nz_p[0], ny = ny_p[0], nx = nx_p[0];
    long long spatial = (long long)nz * ny * nx;
    int b = coords[4 * n + 0];
    int z = coords[4 * n + 1];
    int y = coords[4 * n + 2];
    int x = coords[4 * n + 3];
    // faithful to reference: per-sample index = z*nz + y*nx + x
    long long cell = b * spatial + (long long)z * nz + (long long)y * nx + x;
    idxmap[cell] = n;
}

__global__ __launch_bounds__(128)
void pps_gather_v4(const float* __restrict__ vf,
                   const int* __restrict__ idxmap,
                   const int* __restrict__ nz_p,
                   const int* __restrict__ ny_p,
                   const int* __restrict__ nx_p,
                   float* __restrict__ out,
                   int C, long long ncells) {
    // uniform geometry -> SGPRs
    const int spatial =
        __builtin_amdgcn_readfirstlane(nz_p[0] * ny_p[0] * nx_p[0]);
    const long long nquads = (ncells + 3) >> 2;
    long long q = blockIdx.x * (long long)blockDim.x + threadIdx.x;
    if (q >= nquads) return;

    long long cell = q << 2;
    unsigned int ucell = (unsigned int)cell;          // ncells < 2^31
    unsigned int b = ucell / (unsigned int)spatial;   // 32-bit magic-div
    unsigned int s = ucell - b * (unsigned int)spatial;

    if (cell + 3 < ncells && s + 3 < (unsigned int)spatial && (C & 3) == 0) {
        int4 iv = *reinterpret_cast<const int4*>(idxmap + cell);
        const bool vx = iv.x >= 0, vy = iv.y >= 0, vz = iv.z >= 0, vw = iv.w >= 0;
        const bool any_valid = vx | vy | vz | vw;
        const unsigned long long wave_any = __ballot(any_valid);
        const float* px = vf + (long long)iv.x * C;
        const float* py = vf + (long long)iv.y * C;
        const float* pz = vf + (long long)iv.z * C;
        const float* pw = vf + (long long)iv.w * C;
        float* op0 = out + ((long long)b * C) * spatial + s;

        if (wave_any == 0ULL) {
            // whole wave empty: pure streaming zero-fill, no loads at all
            const v4f zero = {0.f, 0.f, 0.f, 0.f};
            float* op = op0;
            #pragma unroll 8
            for (int cc = 0; cc < C; ++cc) {
                __builtin_nontemporal_store(zero, reinterpret_cast<v4f*>(op));
                op += spatial;
            }
        } else {
            #pragma unroll 4
            for (int cc = 0; cc < C; cc += 4) {
                v4f rx = {0.f, 0.f, 0.f, 0.f};
                v4f ry = rx, rz = rx, rw = rx;
                if (vx) rx = *reinterpret_cast<const v4f*>(px + cc);
                if (vy) ry = *reinterpret_cast<const v4f*>(py + cc);
                if (vz) rz = *reinterpret_cast<const v4f*>(pz + cc);
                if (vw) rw = *reinterpret_cast<const v4f*>(pw + cc);
                float* op = op0 + (long long)cc * spatial;
                v4f o0 = {rx.x, ry.x, rz.x, rw.x};
                v4f o1 = {rx.y, ry.y, rz.y, rw.y};
                v4f o2 = {rx.z, ry.z, rz.z, rw.z};
                v4f o3 = {rx.w, ry.w, rz.w, rw.w};
                __builtin_nontemporal_store(o0, reinterpret_cast<v4f*>(op));
                op += spatial;
                __builtin_nontemporal_store(o1, reinterpret_cast<v4f*>(op));
                op += spatial;
                __builtin_nontemporal_store(o2, reinterpret_cast<v4f*>(op));
                op += spatial;
                __builtin_nontemporal_store(o3, reinterpret_cast<v4f*>(op));
            }
        }
    } else {
        // tail / sample-boundary straddle / odd C: scalar per element
        for (int j = 0; j < 4; ++j) {
            long long cc = cell + j;
            if (cc >= ncells) break;
            long long bb = cc / spatial;
            long long ss = cc - bb * spatial;
            int idx = idxmap[cc];
            for (int c = 0; c < C; ++c)
                out[(bb * C + c) * spatial + ss] =
                    (idx >= 0) ? vf[(long long)idx * C + c] : 0.0f;
        }
    }
}

// -------- fallback path (round-1): memset + direct scatter ----------------
__global__ void pps_scatter_kernel(const float* __restrict__ vf,
                                   const int* __restrict__ coords,
                                   const int* __restrict__ nz_p,
                                   const int* __restrict__ ny_p,
                                   const int* __restrict__ nx_p,
                                   float* __restrict__ out,
                                   int n_points, int C) {
    int idx = blockIdx.x * blockDim.x + threadIdx.x;
    int total = n_points * C;
    if (idx >= total) return;
    int n = idx / C;
    int c = idx - n * C;
    int nz = nz_p[0], ny = ny_p[0], nx = nx_p[0];
    long long spatial = (long long)nz * ny * nx;
    int b = coords[4 * n + 0];
    int z = coords[4 * n + 1];
    int y = coords[4 * n + 2];
    int x = coords[4 * n + 3];
    long long s = (long long)z * nz + (long long)y * nx + (long long)x;
    out[((long long)b * C + c) * spatial + s] = vf[idx];
}

extern "C" void kernel_launch(void* const* d_in, const int* in_sizes, int n_in,
                              void* d_out, int out_size, void* d_ws, size_t ws_size,
                              hipStream_t stream) {
    const float* vf     = (const float*)d_in[0];
    const int*   coords = (const int*)d_in[1];
    const int*   nz_p   = (const int*)d_in[3];
    const int*   ny_p   = (const int*)d_in[4];
    const int*   nx_p   = (const int*)d_in[5];
    float* out = (float*)d_out;

    int n_points = in_sizes[1] / 4;          // coords = [N,4]
    int C        = in_sizes[0] / n_points;   // vf = [N,C]
    long long ncells = (long long)out_size / C;   // B * spatial
    size_t idx_bytes = (size_t)ncells * sizeof(int);

    if (ws_size >= idx_bytes && ncells < 0x7FFFFFFFLL) {
        int* idxmap = (int*)d_ws;
        // pass A: index canvas = -1 (3.4 MB)
        (void)hipMemsetAsync(idxmap, 0xFF, idx_bytes, stream);
        // pass B: scatter point ids (64k 4B writes)
        {
            int block = 256;
            int grid = (n_points + block - 1) / block;
            pps_build_idx<<<grid, block, 0, stream>>>(coords, nz_p, ny_p, nx_p,
                                                      idxmap, n_points);
        }
        // pass C: coalesced gather, full-C per thread, nt stores
        {
            int block = 128;
            long long nquads = (ncells + 3) / 4;
            long long gx = (nquads + block - 1) / block;
            if (gx > 0x7FFFFFFF) gx = 0x7FFFFFFF;
            pps_gather_v4<<<(int)gx, block, 0, stream>>>(vf, idxmap, nz_p, ny_p,
                                                         nx_p, out, C, ncells);
        }
    } else {
        // fallback: memset full canvas + direct scatter
        (void)hipMemsetAsync(d_out, 0, (size_t)out_size * sizeof(float), stream);
        int total = n_points * C;
        int block = 256;
        int grid  = (total + block - 1) / block;
        pps_scatter_kernel<<<grid, block, 0, stream>>>(vf, coords, nz_p, ny_p,
                                                       nx_p, out, n_points, C);
    }
}

// Round 10
// 47.829 us; speedup vs baseline: 1.1231x; 1.1231x over previous
//
#include <hip/hip_runtime.h>

// PointPillarsScatter, round 10: round-6 gather structure (plain stores —
// nt stores regressed 48->54 in round 9) + scalar geometry addressing
// (readfirstlane, 32-bit div) + block=256 so each plane iteration writes a
// 4KB contiguous burst per block (store DRAM locality).

__global__ void pps_build_idx(const int* __restrict__ coords,
                              const int* __restrict__ nz_p,
                              const int* __restrict__ ny_p,
                              const int* __restrict__ nx_p,
                              int* __restrict__ idxmap, int n_points) {
    int n = blockIdx.x * blockDim.x + threadIdx.x;
    if (n >= n_points) return;
    int nz = nz_p[0], ny = ny_p[0], nx = nx_p[0];
    long long spatial = (long long)nz * ny * nx;
    int b = coords[4 * n + 0];
    int z = coords[4 * n + 1];
    int y = coords[4 * n + 2];
    int x = coords[4 * n + 3];
    // faithful to reference: per-sample index = z*nz + y*nx + x
    long long cell = b * spatial + (long long)z * nz + (long long)y * nx + x;
    idxmap[cell] = n;
}

__global__ __launch_bounds__(256)
void pps_gather_v5(const float* __restrict__ vf,
                   const int* __restrict__ idxmap,
                   const int* __restrict__ nz_p,
                   const int* __restrict__ ny_p,
                   const int* __restrict__ nx_p,
                   float* __restrict__ out,
                   int C, long long ncells) {
    // uniform geometry -> SGPR
    const int spatial =
        __builtin_amdgcn_readfirstlane(nz_p[0] * ny_p[0] * nx_p[0]);
    const long long nquads = (ncells + 3) >> 2;
    long long q = blockIdx.x * (long long)blockDim.x + threadIdx.x;
    if (q >= nquads) return;

    long long cell = q << 2;
    unsigned int ucell = (unsigned int)cell;          // ncells < 2^31
    unsigned int b = ucell / (unsigned int)spatial;
    unsigned int s = ucell - b * (unsigned int)spatial;

    if (cell + 3 < ncells && s + 3 < (unsigned int)spatial && (C & 3) == 0) {
        // fast path: quad inside one sample, channels divisible by 4
        int4 iv = *reinterpret_cast<const int4*>(idxmap + cell);
        const bool vx = iv.x >= 0, vy = iv.y >= 0, vz = iv.z >= 0, vw = iv.w >= 0;
        const float* px = vf + (long long)iv.x * C;
        const float* py = vf + (long long)iv.y * C;
        const float* pz = vf + (long long)iv.z * C;
        const float* pw = vf + (long long)iv.w * C;
        float* op0 = out + ((long long)b * C) * spatial + s;

        #pragma unroll 4
        for (int cc = 0; cc < C; cc += 4) {
            float4 rx = make_float4(0.f, 0.f, 0.f, 0.f);
            float4 ry = rx, rz = rx, rw = rx;
            if (vx) rx = *reinterpret_cast<const float4*>(px + cc);
            if (vy) ry = *reinterpret_cast<const float4*>(py + cc);
            if (vz) rz = *reinterpret_cast<const float4*>(pz + cc);
            if (vw) rw = *reinterpret_cast<const float4*>(pw + cc);
            float* op = op0 + (long long)cc * spatial;
            *reinterpret_cast<float4*>(op) = make_float4(rx.x, ry.x, rz.x, rw.x);
            op += spatial;
            *reinterpret_cast<float4*>(op) = make_float4(rx.y, ry.y, rz.y, rw.y);
            op += spatial;
            *reinterpret_cast<float4*>(op) = make_float4(rx.z, ry.z, rz.z, rw.z);
            op += spatial;
            *reinterpret_cast<float4*>(op) = make_float4(rx.w, ry.w, rz.w, rw.w);
        }
    } else {
        // tail / sample-boundary straddle / odd C: scalar per element
        for (int j = 0; j < 4; ++j) {
            long long cc = cell + j;
            if (cc >= ncells) break;
            long long bb = cc / spatial;
            long long ss = cc - bb * spatial;
            int idx = idxmap[cc];
            for (int c = 0; c < C; ++c)
                out[(bb * C + c) * spatial + ss] =
                    (idx >= 0) ? vf[(long long)idx * C + c] : 0.0f;
        }
    }
}

// -------- fallback path (round-1): memset + direct scatter ----------------
__global__ void pps_scatter_kernel(const float* __restrict__ vf,
                                   const int* __restrict__ coords,
                                   const int* __restrict__ nz_p,
                                   const int* __restrict__ ny_p,
                                   const int* __restrict__ nx_p,
                                   float* __restrict__ out,
                                   int n_points, int C) {
    int idx = blockIdx.x * blockDim.x + threadIdx.x;
    int total = n_points * C;
    if (idx >= total) return;
    int n = idx / C;
    int c = idx - n * C;
    int nz = nz_p[0], ny = ny_p[0], nx = nx_p[0];
    long long spatial = (long long)nz * ny * nx;
    int b = coords[4 * n + 0];
    int z = coords[4 * n + 1];
    int y = coords[4 * n + 2];
    int x = coords[4 * n + 3];
    long long s = (long long)z * nz + (long long)y * nx + (long long)x;
    out[((long long)b * C + c) * spatial + s] = vf[idx];
}

extern "C" void kernel_launch(void* const* d_in, const int* in_sizes, int n_in,
                              void* d_out, int out_size, void* d_ws, size_t ws_size,
                              hipStream_t stream) {
    const float* vf     = (const float*)d_in[0];
    const int*   coords = (const int*)d_in[1];
    const int*   nz_p   = (const int*)d_in[3];
    const int*   ny_p   = (const int*)d_in[4];
    const int*   nx_p   = (const int*)d_in[5];
    float* out = (float*)d_out;

    int n_points = in_sizes[1] / 4;          // coords = [N,4]
    int C        = in_sizes[0] / n_points;   // vf = [N,C]
    long long ncells = (long long)out_size / C;   // B * spatial
    size_t idx_bytes = (size_t)ncells * sizeof(int);

    if (ws_size >= idx_bytes && ncells < 0x7FFFFFFFLL) {
        int* idxmap = (int*)d_ws;
        // pass A: index canvas = -1 (3.4 MB)
        (void)hipMemsetAsync(idxmap, 0xFF, idx_bytes, stream);
        // pass B: scatter point ids (64k 4B writes)
        {
            int block = 256;
            int grid = (n_points + block - 1) / block;
            pps_build_idx<<<grid, block, 0, stream>>>(coords, nz_p, ny_p, nx_p,
                                                      idxmap, n_points);
        }
        // pass C: coalesced gather, full-C per thread, block=256 (4KB bursts)
        {
            int block = 256;
            long long nquads = (ncells + 3) / 4;
            long long gx = (nquads + block - 1) / block;
            if (gx > 0x7FFFFFFF) gx = 0x7FFFFFFF;
            pps_gather_v5<<<(int)gx, block, 0, stream>>>(vf, idxmap, nz_p, ny_p,
                                                         nx_p, out, C, ncells);
        }
    } else {
        // fallback: memset full canvas + direct scatter
        (void)hipMemsetAsync(d_out, 0, (size_t)out_size * sizeof(float), stream);
        int total = n_points * C;
        int block = 256;
        int grid  = (total + block - 1) / block;
        pps_scatter_kernel<<<grid, block, 0, stream>>>(vf, coords, nz_p, ny_p,
                                                       nx_p, out, n_points, C);
    }
}

// Round 11
// 47.692 us; speedup vs baseline: 1.1263x; 1.0029x over previous
//
#include <hip/hip_runtime.h>

// PointPillarsScatter, round 11: vmem-issue reduction via block-level load
// compaction. Gather per 256-thread block (1024 cells x 64 channels):
//   phase 1: idx quad -> compact LDS slot list (slot 0 = zero row)
//   phase 2: cooperative vf row load (16 thr x float4 per 256B row) into LDS
//   phase 3: ds_read_b128 fragments + register transpose + coalesced float4
//            stores (vmem issue per wave: 129 -> ~70)
// Overflow (>192 valid cells/block) falls back block-uniformly to direct
// global masked loads. Host picks kernels by C/ws_size.

#define PPS_MAXSLOTS 192
#define PPS_ROWSTRIDE 68   // 64 + 4 pad: slot*68 breaks the slot*64 bank alias

__global__ void pps_build_idx(const int* __restrict__ coords,
                              const int* __restrict__ nz_p,
                              const int* __restrict__ ny_p,
                              const int* __restrict__ nx_p,
                              int* __restrict__ idxmap, int n_points) {
    int n = blockIdx.x * blockDim.x + threadIdx.x;
    if (n >= n_points) return;
    int nz = nz_p[0], ny = ny_p[0], nx = nx_p[0];
    long long spatial = (long long)nz * ny * nx;
    int b = coords[4 * n + 0];
    int z = coords[4 * n + 1];
    int y = coords[4 * n + 2];
    int x = coords[4 * n + 3];
    // faithful to reference: per-sample index = z*nz + y*nx + x
    long long cell = b * spatial + (long long)z * nz + (long long)y * nx + x;
    idxmap[cell] = n;
}

// C == 64 specialized, spatial % 4 == 0, ncells % 4 == 0 (checked on host)
__global__ __launch_bounds__(256)
void pps_gather_v6(const float* __restrict__ vf,
                   const int* __restrict__ idxmap,
                   const int* __restrict__ nz_p,
                   const int* __restrict__ ny_p,
                   const int* __restrict__ nx_p,
                   float* __restrict__ out,
                   long long ncells) {
    __shared__ float rows[(PPS_MAXSLOTS + 1) * PPS_ROWSTRIDE];
    __shared__ int slots_idx[PPS_MAXSLOTS + 1];
    __shared__ int cnt;

    const int spatial =
        __builtin_amdgcn_readfirstlane(nz_p[0] * ny_p[0] * nx_p[0]);
    const int t = threadIdx.x;
    if (t == 0) cnt = 0;
    __syncthreads();

    long long q = blockIdx.x * 256LL + t;
    long long cell = q << 2;
    const bool in_range = (cell + 3 < ncells);

    int4 iv = make_int4(-1, -1, -1, -1);
    int sx = 0, sy = 0, sz = 0, sw = 0;
    unsigned int b = 0, s = 0;
    if (in_range) {
        unsigned int ucell = (unsigned int)cell;
        b = ucell / (unsigned int)spatial;
        s = ucell - b * (unsigned int)spatial;
        iv = *reinterpret_cast<const int4*>(idxmap + cell);
        // phase 1: register valid cells into the compact slot list
        if (iv.x >= 0) { int sl = atomicAdd(&cnt, 1);
            if (sl < PPS_MAXSLOTS) { sx = sl + 1; slots_idx[sl + 1] = iv.x; } else sx = -1; }
        if (iv.y >= 0) { int sl = atomicAdd(&cnt, 1);
            if (sl < PPS_MAXSLOTS) { sy = sl + 1; slots_idx[sl + 1] = iv.y; } else sy = -1; }
        if (iv.z >= 0) { int sl = atomicAdd(&cnt, 1);
            if (sl < PPS_MAXSLOTS) { sz = sl + 1; slots_idx[sl + 1] = iv.z; } else sz = -1; }
        if (iv.w >= 0) { int sl = atomicAdd(&cnt, 1);
            if (sl < PPS_MAXSLOTS) { sw = sl + 1; slots_idx[sl + 1] = iv.w; } else sw = -1; }
    }
    __syncthreads();

    const int total = cnt;
    const int nv = total < PPS_MAXSLOTS ? total : PPS_MAXSLOTS;
    const int part = t & 15;                     // 16 x float4 per 256B row
    // zero row (slot 0)
    if (t < 16) {
        float4 zero = make_float4(0.f, 0.f, 0.f, 0.f);
        *reinterpret_cast<float4*>(&rows[part * 4]) = zero;
    }
    // phase 2: cooperative row loads (vmem: ~nv/4 instrs per wave group)
    for (int slot = 1 + (t >> 4); slot <= nv; slot += 16) {
        int src = slots_idx[slot];
        float4 v = *reinterpret_cast<const float4*>(vf + src * 64 + part * 4);
        *reinterpret_cast<float4*>(&rows[slot * PPS_ROWSTRIDE + part * 4]) = v;
    }
    __syncthreads();

    if (!in_range) {
        // tail: scalar per element (never taken when ncells%4==0)
        for (int j = 0; j < 4; ++j) {
            long long cc = cell + j;
            if (cc < 0 || cc >= ncells) continue;
            long long bb = cc / spatial;
            long long ss = cc - bb * spatial;
            int idx = idxmap[cc];
            for (int c = 0; c < 64; ++c)
                out[(bb * 64 + c) * (long long)spatial + ss] =
                    (idx >= 0) ? vf[(long long)idx * 64 + c] : 0.0f;
        }
        return;
    }

    float* op0 = out + ((long long)b * 64) * spatial + s;

    if (total <= PPS_MAXSLOTS) {
        // phase 3 (common): all fragments from LDS; zero slot broadcasts
        #pragma unroll 4
        for (int cc = 0; cc < 64; cc += 4) {
            float4 rx = *reinterpret_cast<const float4*>(&rows[sx * PPS_ROWSTRIDE + cc]);
            float4 ry = *reinterpret_cast<const float4*>(&rows[sy * PPS_ROWSTRIDE + cc]);
            float4 rz = *reinterpret_cast<const float4*>(&rows[sz * PPS_ROWSTRIDE + cc]);
            float4 rw = *reinterpret_cast<const float4*>(&rows[sw * PPS_ROWSTRIDE + cc]);
            float* op = op0 + (long long)cc * spatial;
            *reinterpret_cast<float4*>(op) = make_float4(rx.x, ry.x, rz.x, rw.x);
            op += spatial;
            *reinterpret_cast<float4*>(op) = make_float4(rx.y, ry.y, rz.y, rw.y);
            op += spatial;
            *reinterpret_cast<float4*>(op) = make_float4(rx.z, ry.z, rz.z, rw.z);
            op += spatial;
            *reinterpret_cast<float4*>(op) = make_float4(rx.w, ry.w, rz.w, rw.w);
        }
    } else {
        // overflow (block-uniform, ~never): direct global masked loads (v5 path)
        const bool vx = iv.x >= 0, vy = iv.y >= 0, vz = iv.z >= 0, vw = iv.w >= 0;
        const float* px = vf + (long long)iv.x * 64;
        const float* py = vf + (long long)iv.y * 64;
        const float* pz = vf + (long long)iv.z * 64;
        const float* pw = vf + (long long)iv.w * 64;
        #pragma unroll 4
        for (int cc = 0; cc < 64; cc += 4) {
            float4 rx = make_float4(0.f, 0.f, 0.f, 0.f);
            float4 ry = rx, rz = rx, rw = rx;
            if (vx) rx = *reinterpret_cast<const float4*>(px + cc);
            if (vy) ry = *reinterpret_cast<const float4*>(py + cc);
            if (vz) rz = *reinterpret_cast<const float4*>(pz + cc);
            if (vw) rw = *reinterpret_cast<const float4*>(pw + cc);
            float* op = op0 + (long long)cc * spatial;
            *reinterpret_cast<float4*>(op) = make_float4(rx.x, ry.x, rz.x, rw.x);
            op += spatial;
            *reinterpret_cast<float4*>(op) = make_float4(rx.y, ry.y, rz.y, rw.y);
            op += spatial;
            *reinterpret_cast<float4*>(op) = make_float4(rx.z, ry.z, rz.z, rw.z);
            op += spatial;
            *reinterpret_cast<float4*>(op) = make_float4(rx.w, ry.w, rz.w, rw.w);
        }
    }
}

// -------- generic gather (round-10 v5) for C != 64 etc. -------------------
__global__ __launch_bounds__(256)
void pps_gather_v5(const float* __restrict__ vf,
                   const int* __restrict__ idxmap,
                   const int* __restrict__ nz_p,
                   const int* __restrict__ ny_p,
                   const int* __restrict__ nx_p,
                   float* __restrict__ out,
                   int C, long long ncells) {
    const int spatial =
        __builtin_amdgcn_readfirstlane(nz_p[0] * ny_p[0] * nx_p[0]);
    const long long nquads = (ncells + 3) >> 2;
    long long q = blockIdx.x * (long long)blockDim.x + threadIdx.x;
    if (q >= nquads) return;
    long long cell = q << 2;
    unsigned int ucell = (unsigned int)cell;
    unsigned int b = ucell / (unsigned int)spatial;
    unsigned int s = ucell - b * (unsigned int)spatial;

    if (cell + 3 < ncells && s + 3 < (unsigned int)spatial && (C & 3) == 0) {
        int4 iv = *reinterpret_cast<const int4*>(idxmap + cell);
        const bool vx = iv.x >= 0, vy = iv.y >= 0, vz = iv.z >= 0, vw = iv.w >= 0;
        const float* px = vf + (long long)iv.x * C;
        const float* py = vf + (long long)iv.y * C;
        const float* pz = vf + (long long)iv.z * C;
        const float* pw = vf + (long long)iv.w * C;
        float* op0 = out + ((long long)b * C) * spatial + s;
        #pragma unroll 4
        for (int cc = 0; cc < C; cc += 4) {
            float4 rx = make_float4(0.f, 0.f, 0.f, 0.f);
            float4 ry = rx, rz = rx, rw = rx;
            if (vx) rx = *reinterpret_cast<const float4*>(px + cc);
            if (vy) ry = *reinterpret_cast<const float4*>(py + cc);
            if (vz) rz = *reinterpret_cast<const float4*>(pz + cc);
            if (vw) rw = *reinterpret_cast<const float4*>(pw + cc);
            float* op = op0 + (long long)cc * spatial;
            *reinterpret_cast<float4*>(op) = make_float4(rx.x, ry.x, rz.x, rw.x);
            op += spatial;
            *reinterpret_cast<float4*>(op) = make_float4(rx.y, ry.y, rz.y, rw.y);
            op += spatial;
            *reinterpret_cast<float4*>(op) = make_float4(rx.z, ry.z, rz.z, rw.z);
            op += spatial;
            *reinterpret_cast<float4*>(op) = make_float4(rx.w, ry.w, rz.w, rw.w);
        }
    } else {
        for (int j = 0; j < 4; ++j) {
            long long cc = cell + j;
            if (cc >= ncells) break;
            long long bb = cc / spatial;
            long long ss = cc - bb * spatial;
            int idx = idxmap[cc];
            for (int c = 0; c < C; ++c)
                out[(bb * C + c) * (long long)spatial + ss] =
                    (idx >= 0) ? vf[(long long)idx * C + c] : 0.0f;
        }
    }
}

// -------- fallback path (round-1): memset + direct scatter ----------------
__global__ void pps_scatter_kernel(const float* __restrict__ vf,
                                   const int* __restrict__ coords,
                                   const int* __restrict__ nz_p,
                                   const int* __restrict__ ny_p,
                                   const int* __restrict__ nx_p,
                                   float* __restrict__ out,
                                   int n_points, int C) {
    int idx = blockIdx.x * blockDim.x + threadIdx.x;
    int total = n_points * C;
    if (idx >= total) return;
    int n = idx / C;
    int c = idx - n * C;
    int nz = nz_p[0], ny = ny_p[0], nx = nx_p[0];
    long long spatial = (long long)nz * ny * nx;
    int b = coords[4 * n + 0];
    int z = coords[4 * n + 1];
    int y = coords[4 * n + 2];
    int x = coords[4 * n + 3];
    long long s = (long long)z * nz + (long long)y * nx + (long long)x;
    out[((long long)b * C + c) * spatial + s] = vf[idx];
}

extern "C" void kernel_launch(void* const* d_in, const int* in_sizes, int n_in,
                              void* d_out, int out_size, void* d_ws, size_t ws_size,
                              hipStream_t stream) {
    const float* vf     = (const float*)d_in[0];
    const int*   coords = (const int*)d_in[1];
    const int*   nz_p   = (const int*)d_in[3];
    const int*   ny_p   = (const int*)d_in[4];
    const int*   nx_p   = (const int*)d_in[5];
    float* out = (float*)d_out;

    int n_points = in_sizes[1] / 4;          // coords = [N,4]
    int C        = in_sizes[0] / n_points;   // vf = [N,C]
    long long ncells = (long long)out_size / C;   // B * spatial
    size_t idx_bytes = (size_t)ncells * sizeof(int);

    if (ws_size >= idx_bytes && ncells < 0x7FFFFFFFLL) {
        int* idxmap = (int*)d_ws;
        (void)hipMemsetAsync(idxmap, 0xFF, idx_bytes, stream);
        {
            int block = 256;
            int grid = (n_points + block - 1) / block;
            pps_build_idx<<<grid, block, 0, stream>>>(coords, nz_p, ny_p, nx_p,
                                                      idxmap, n_points);
        }
        long long nquads = (ncells + 3) / 4;
        if (C == 64 && (ncells & 3) == 0) {
            long long gx = (nquads + 255) / 256;
            if (gx > 0x7FFFFFFF) gx = 0x7FFFFFFF;
            pps_gather_v6<<<(int)gx, 256, 0, stream>>>(vf, idxmap, nz_p, ny_p,
                                                       nx_p, out, ncells);
        } else {
            long long gx = (nquads + 255) / 256;
            if (gx > 0x7FFFFFFF) gx = 0x7FFFFFFF;
            pps_gather_v5<<<(int)gx, 256, 0, stream>>>(vf, idxmap, nz_p, ny_p,
                                                       nx_p, out, C, ncells);
        }
    } else {
        (void)hipMemsetAsync(d_out, 0, (size_t)out_size * sizeof(float), stream);
        int total = n_points * C;
        int block = 256;
        int grid  = (total + block - 1) / block;
        pps_scatter_kernel<<<grid, block, 0, stream>>>(vf, coords, nz_p, ny_p,
                                                       nx_p, out, n_points, C);
    }
}